// Round 3
// baseline (110.781 us; speedup 1.0000x reference)
//
#include <hip/hip_runtime.h>
#include <math.h>
#include <limits.h>

// out[b,h,w,c] = vgg[b,h,w,c] - t[b,h,w]
//   t = (a > 0.5f) ? a : 0,  a[b,h,w] = interm[b,h,w, argmax_c logits[b,c]]
// B=256, H=W=7 (P=49 positions), C_in=1000, C_out=512. All fp32.
//
// Two-kernel split (primary path):
//   1) cam_prep:  one block per sample computes argmax + gathers/thresholds the
//      49 CAM values -> t[256][49] in workspace. Removes the redundant argmax
//      (4x logits re-read) and the uncoalesced-gather latency prefix from the
//      streaming path.
//   2) cam_sub_stream: pure float4 streaming subtract at HBM rate, 2048 blocks,
//      nontemporal load/store (single-touch data, don't pollute L2/L3).
//      NOTE: __builtin_nontemporal_* requires a clang ext_vector_type, not
//      HIP's float4 class -> use fvec4 below.
// Fallback path (if workspace missing/undersized): the round-0 fused kernel,
//   harness-verified at 107.6 us. Guarantees no invalid d_ws dereference.

#define NB     256      // batch
#define NP     49       // 7*7 positions
#define CIN    1000     // interm / logits channels
#define COUT   512      // vgg channels
#define VEC_PER_SAMPLE (NP * COUT / 4)   // 6272 float4 per sample
#define SBLK   8        // streaming blocks per sample -> 2048 blocks total
#define KBLK   4        // fused-fallback blocks per sample

typedef float fvec4 __attribute__((ext_vector_type(4)));  // clang vector: ok for nontemporal builtins

// ---------------------------------------------------------------- primary ----

__global__ __launch_bounds__(256) void cam_prep(
    const float* __restrict__ interm,
    const float* __restrict__ logits,
    float* __restrict__ t)
{
    const int b   = blockIdx.x;
    const int tid = threadIdx.x;

    // ---- per-sample argmax over logits[b, 0..999] (first-index tie-break,
    //      matching jnp.argmax) ----
    const float* lg = logits + b * CIN;
    float bv = -INFINITY;
    int   bi = INT_MAX;
    for (int i = tid; i < CIN; i += 256) {
        float v = lg[i];
        if (v > bv || (v == bv && i < bi)) { bv = v; bi = i; }
    }
    // wave-64 butterfly-down reduce with first-index tie-break
    for (int off = 32; off >= 1; off >>= 1) {
        float ov = __shfl_down(bv, off, 64);
        int   oi = __shfl_down(bi, off, 64);
        if (ov > bv || (ov == bv && oi < bi)) { bv = ov; bi = oi; }
    }
    __shared__ float wv[4];
    __shared__ int   wi[4];
    __shared__ int   s_idx;
    const int wave = tid >> 6;
    if ((tid & 63) == 0) { wv[wave] = bv; wi[wave] = bi; }
    __syncthreads();
    if (tid == 0) {
        float v = wv[0]; int i = wi[0];
        #pragma unroll
        for (int w = 1; w < 4; ++w)
            if (wv[w] > v || (wv[w] == v && wi[w] < i)) { v = wv[w]; i = wi[w]; }
        s_idx = i;
    }
    __syncthreads();
    const int idx = s_idx;

    // ---- gather + threshold the 49 CAM values -> workspace ----
    if (tid < NP) {
        float a = interm[((size_t)b * NP + tid) * CIN + idx];
        t[b * NP + tid] = (a > 0.5f) ? a : 0.0f;
    }
}

__global__ __launch_bounds__(256) void cam_sub_stream(
    const float* __restrict__ vgg,
    const float* __restrict__ t,
    float* __restrict__ out)
{
    const int b     = blockIdx.x >> 3;      // SBLK = 8
    const int chunk = blockIdx.x & (SBLK - 1);
    const int tid   = threadIdx.x;

    // 49 thresholded CAM values for this sample (L2-hot: written by cam_prep)
    __shared__ float s_a[NP];
    if (tid < NP) s_a[tid] = t[b * NP + tid];
    __syncthreads();

    const fvec4* __restrict__ vgg4 = (const fvec4*)(vgg + (size_t)b * NP * COUT);
    fvec4*       __restrict__ out4 = (fvec4*)(out + (size_t)b * NP * COUT);
    // 6272 float4 per sample, 2048 threads/sample -> 3-4 iterations each
    for (int v = chunk * 256 + tid; v < VEC_PER_SAMPLE; v += SBLK * 256) {
        const float a = s_a[v >> 7];        // 512/4 = 128 float4 per position
        fvec4 x = __builtin_nontemporal_load(&vgg4[v]);
        x -= a;
        __builtin_nontemporal_store(x, &out4[v]);
    }
}

// --------------------------------------------------------------- fallback ----
// Round-0 fused kernel (harness-verified). Used only when d_ws is unusable.

__global__ __launch_bounds__(256) void cam_sub_fused(
    const float* __restrict__ vgg,
    const float* __restrict__ interm,
    const float* __restrict__ logits,
    float* __restrict__ out)
{
    const int b     = blockIdx.x / KBLK;
    const int chunk = blockIdx.x % KBLK;
    const int tid   = threadIdx.x;

    const float* lg = logits + b * CIN;
    float bv = -INFINITY;
    int   bi = INT_MAX;
    for (int i = tid; i < CIN; i += 256) {
        float v = lg[i];
        if (v > bv || (v == bv && i < bi)) { bv = v; bi = i; }
    }
    for (int off = 32; off >= 1; off >>= 1) {
        float ov = __shfl_down(bv, off, 64);
        int   oi = __shfl_down(bi, off, 64);
        if (ov > bv || (ov == bv && oi < bi)) { bv = ov; bi = oi; }
    }
    __shared__ float wv[4];
    __shared__ int   wi[4];
    __shared__ int   s_idx;
    __shared__ float s_a[NP];
    const int wave = tid >> 6;
    if ((tid & 63) == 0) { wv[wave] = bv; wi[wave] = bi; }
    __syncthreads();
    if (tid == 0) {
        float v = wv[0]; int i = wi[0];
        #pragma unroll
        for (int w = 1; w < 4; ++w)
            if (wv[w] > v || (wv[w] == v && wi[w] < i)) { v = wv[w]; i = wi[w]; }
        s_idx = i;
    }
    __syncthreads();
    const int idx = s_idx;

    if (tid < NP) {
        float a = interm[((size_t)b * NP + tid) * CIN + idx];
        s_a[tid] = (a > 0.5f) ? a : 0.0f;
    }
    __syncthreads();

    const float4* __restrict__ vgg4 = (const float4*)(vgg + (size_t)b * NP * COUT);
    float4*       __restrict__ out4 = (float4*)(out + (size_t)b * NP * COUT);
    for (int v = chunk * 256 + tid; v < VEC_PER_SAMPLE; v += KBLK * 256) {
        const float a = s_a[v >> 7];
        float4 x = vgg4[v];
        x.x -= a; x.y -= a; x.z -= a; x.w -= a;
        out4[v] = x;
    }
}

// ----------------------------------------------------------------- launch ----

extern "C" void kernel_launch(void* const* d_in, const int* in_sizes, int n_in,
                              void* d_out, int out_size, void* d_ws, size_t ws_size,
                              hipStream_t stream) {
    const float* vgg    = (const float*)d_in[0];  // [256,7,7,512]
    const float* interm = (const float*)d_in[1];  // [256,7,7,1000]
    const float* logits = (const float*)d_in[2];  // [256,1000]
    float* out = (float*)d_out;                   // [256,7,7,512]

    const size_t t_bytes = (size_t)NB * NP * sizeof(float);   // 50 KB
    if (d_ws != nullptr && ws_size >= t_bytes) {
        float* t = (float*)d_ws;                  // [256,49] thresholded CAM
        hipLaunchKernelGGL(cam_prep, dim3(NB), dim3(256), 0, stream,
                           interm, logits, t);
        hipLaunchKernelGGL(cam_sub_stream, dim3(NB * SBLK), dim3(256), 0, stream,
                           vgg, t, out);
    } else {
        hipLaunchKernelGGL(cam_sub_fused, dim3(NB * KBLK), dim3(256), 0, stream,
                           vgg, interm, logits, out);
    }
}

// Round 4
// 107.978 us; speedup vs baseline: 1.0260x; 1.0260x over previous
//
#include <hip/hip_runtime.h>
#include <math.h>
#include <limits.h>

// out[b,h,w,c] = vgg[b,h,w,c] - t[b,h,w]
//   t = (a > 0.5f) ? a : 0,  a[b,h,w] = interm[b,h,w, argmax_c logits[b,c]]
// B=256, H=W=7 (P=49 positions), C_in=1000, C_out=512. All fp32.
//
// Fused single kernel (round-3 split was 3-4us SLOWER: prep->stream
// serialization + inter-dispatch gap outweighed the removed argmax
// redundancy, and nt hints forfeit cache residency for zero BW gain).
// vs round-0 fused baseline (107.6us):
//   - KBLK 4 -> 8: 2048 blocks = 8 blocks/CU = 32 waves/CU (max occupancy)
//     during the streaming phase, matching the harness fill kernels' 6.5 TB/s
//     regime. Redundant logits traffic 8MB ~= 1.3us of BW - negligible.
//   - argmax loads float4-vectorized: one dwordx4 per thread (250 of 256)
//     instead of 4 strided scalars -> shorter latency prefix.

#define NB     256      // batch
#define NP     49       // 7*7 positions
#define CIN    1000     // interm / logits channels
#define COUT   512      // vgg channels
#define VEC_PER_SAMPLE (NP * COUT / 4)   // 6272 float4 per sample
#define KBLK   8        // blocks per sample -> 2048 blocks total

__global__ __launch_bounds__(256) void cam_sub_fused(
    const float* __restrict__ vgg,
    const float* __restrict__ interm,
    const float* __restrict__ logits,
    float* __restrict__ out)
{
    const int b     = blockIdx.x >> 3;        // KBLK = 8
    const int chunk = blockIdx.x & (KBLK - 1);
    const int tid   = threadIdx.x;

    // ---- per-sample argmax over logits[b, 0..999] (first-index tie-break,
    //      matching jnp.argmax). 1000 = 250 float4: one vector load/thread. ----
    const float4* __restrict__ lg4 = (const float4*)(logits + b * CIN);
    float bv = -INFINITY;
    int   bi = INT_MAX;
    if (tid < CIN / 4) {
        float4 v = lg4[tid];
        bv = v.x; bi = 4 * tid;
        if (v.y > bv) { bv = v.y; bi = 4 * tid + 1; }   // strictly-greater keeps
        if (v.z > bv) { bv = v.z; bi = 4 * tid + 2; }   // first index within the 4
        if (v.w > bv) { bv = v.w; bi = 4 * tid + 3; }
    }
    // wave-64 butterfly-down reduce with first-index tie-break
    for (int off = 32; off >= 1; off >>= 1) {
        float ov = __shfl_down(bv, off, 64);
        int   oi = __shfl_down(bi, off, 64);
        if (ov > bv || (ov == bv && oi < bi)) { bv = ov; bi = oi; }
    }
    __shared__ float wv[4];
    __shared__ int   wi[4];
    __shared__ int   s_idx;
    __shared__ float s_a[NP];
    const int wave = tid >> 6;
    if ((tid & 63) == 0) { wv[wave] = bv; wi[wave] = bi; }
    __syncthreads();
    if (tid == 0) {
        float v = wv[0]; int i = wi[0];
        #pragma unroll
        for (int w = 1; w < 4; ++w)
            if (wv[w] > v || (wv[w] == v && wi[w] < i)) { v = wv[w]; i = wi[w]; }
        s_idx = i;
    }
    __syncthreads();
    const int idx = s_idx;

    // ---- gather + threshold the 49 CAM values into LDS ----
    if (tid < NP) {
        float a = interm[((size_t)b * NP + tid) * CIN + idx];
        s_a[tid] = (a > 0.5f) ? a : 0.0f;
    }
    __syncthreads();

    // ---- streaming subtract, float4-vectorized, coalesced ----
    const float4* __restrict__ vgg4 = (const float4*)(vgg + (size_t)b * NP * COUT);
    float4*       __restrict__ out4 = (float4*)(out + (size_t)b * NP * COUT);
    for (int v = chunk * 256 + tid; v < VEC_PER_SAMPLE; v += KBLK * 256) {
        const float a = s_a[v >> 7];   // 512/4 = 128 float4 per position
        float4 x = vgg4[v];
        x.x -= a; x.y -= a; x.z -= a; x.w -= a;
        out4[v] = x;
    }
}

extern "C" void kernel_launch(void* const* d_in, const int* in_sizes, int n_in,
                              void* d_out, int out_size, void* d_ws, size_t ws_size,
                              hipStream_t stream) {
    const float* vgg    = (const float*)d_in[0];  // [256,7,7,512]
    const float* interm = (const float*)d_in[1];  // [256,7,7,1000]
    const float* logits = (const float*)d_in[2];  // [256,1000]
    float* out = (float*)d_out;                   // [256,7,7,512]

    hipLaunchKernelGGL(cam_sub_fused, dim3(NB * KBLK), dim3(256), 0, stream,
                       vgg, interm, logits, out);
}